// Round 4
// baseline (263.118 us; speedup 1.0000x reference)
//
#include <hip/hip_runtime.h>

#define EMBED 128
#define NPATH 32
#define BATCH 4096
#define DIN 768
#define C1 128
#define C2 32

__device__ __forceinline__ float sel3(float a0, float a1, float a2, int m) {
    float r = a0;
    r = (m == 1) ? a1 : r;
    r = (m == 2) ? a2 : r;
    return r;
}

__device__ __forceinline__ float4 sel3q(const float4 a[3], int m) {
    float4 r;
    r.x = sel3(a[0].x, a[1].x, a[2].x, m);
    r.y = sel3(a[0].y, a[1].y, a[2].y, m);
    r.z = sel3(a[0].z, a[1].z, a[2].z, m);
    r.w = sel3(a[0].w, a[1].w, a[2].w, m);
    return r;
}

__device__ __forceinline__ float4 chain_step(float4 x, float4 y, float4 wm, float4 bm) {
    float4 r;
    r.x = fmaxf(fmaf(x.x * wm.x, y.x, bm.x), 0.f);
    r.y = fmaxf(fmaf(x.y * wm.y, y.y, bm.y), 0.f);
    r.z = fmaxf(fmaf(x.z * wm.z, y.z, bm.z), 0.f);
    r.w = fmaxf(fmaf(x.w * wm.w, y.w, bm.w), 0.f);
    return r;
}

// One group-unit for batch row b. 256 threads: dl = tid&31 owns dims 4*dl..4*dl+3
// (float4), pq = tid>>5 (0..7) owns paths p = pq, pq+8, pq+16, pq+24.
// (Round-0 verified body, 85us; SW pipelining measured neutral in round 2.)
template<int L>
__device__ __forceinline__ void group_body(
    int b, const int* __restrict__ ent, const int* __restrict__ mid,
    const float* __restrict__ counts, const float4* __restrict__ E4,
    const float4* __restrict__ W4, const float4* __restrict__ B4,
    float* __restrict__ h, int gcol, int* s_idx, float4* s_red)
{
    const int tid = threadIdx.x;
    const int dl = tid & 31;
    const int pq = tid >> 5;

    int* s_ent = s_idx;
    int* s_mid = s_idx + NPATH * (L + 1);
    float* s_cnt = (float*)(s_idx + NPATH * (2 * L + 1));

    const int* entb = ent + (size_t)b * (NPATH * (L + 1));
    const int* midb = mid + (size_t)b * (NPATH * L);
    for (int i = tid; i < NPATH * (L + 1); i += 256) s_ent[i] = entb[i];
    for (int i = tid; i < NPATH * L; i += 256) s_mid[i] = midb[i];
    if (tid < NPATH) s_cnt[tid] = counts[(size_t)b * NPATH + tid];
    __syncthreads();

    float4 Wr[3], Br[3];
#pragma unroll
    for (int m = 0; m < 3; ++m) {
        Wr[m] = W4[m * 32 + dl];
        Br[m] = B4[m * 32 + dl];
    }

    float4 n1 = make_float4(0.f, 0.f, 0.f, 0.f);
    float4 n2 = make_float4(0.f, 0.f, 0.f, 0.f);

#pragma unroll 2
    for (int j = 0; j < NPATH / 8; ++j) {
        const int p = pq + 8 * j;
        int ei[L + 1], mi[L];
#pragma unroll
        for (int i = 0; i <= L; ++i) ei[i] = s_ent[p * (L + 1) + i];
#pragma unroll
        for (int i = 0; i < L; ++i) mi[i] = s_mid[p * L + i];

        float4 e[L + 1];
#pragma unroll
        for (int i = 0; i <= L; ++i) e[i] = E4[(size_t)ei[i] * 32 + dl];
        const float c = s_cnt[p];

        float4 x = e[0];
#pragma unroll
        for (int i = 0; i < L; ++i)
            x = chain_step(x, e[i + 1], sel3q(Wr, mi[i]), sel3q(Br, mi[i]));

        const float4 yl = e[L];
        float4 x2 = yl;
#pragma unroll
        for (int i = L - 1; i >= 0; --i)
            x2 = chain_step(x2, yl, sel3q(Wr, mi[i]), sel3q(Br, mi[i]));

        n1.x = fmaf(c, x.x, n1.x); n1.y = fmaf(c, x.y, n1.y);
        n1.z = fmaf(c, x.z, n1.z); n1.w = fmaf(c, x.w, n1.w);
        n2.x = fmaf(c, x2.x, n2.x); n2.y = fmaf(c, x2.y, n2.y);
        n2.z = fmaf(c, x2.z, n2.z); n2.w = fmaf(c, x2.w, n2.w);
    }

    s_red[(pq * 2 + 0) * 32 + dl] = n1;
    s_red[(pq * 2 + 1) * 32 + dl] = n2;
    __syncthreads();
    if (tid < 64) {
        const int half = tid >> 5, dq = tid & 31;
        float4 a = s_red[(0 * 2 + half) * 32 + dq];
#pragma unroll
        for (int q = 1; q < 8; ++q) {
            float4 t = s_red[(q * 2 + half) * 32 + dq];
            a.x += t.x; a.y += t.y; a.z += t.z; a.w += t.w;
        }
        float den = 0.f;
#pragma unroll
        for (int p = 0; p < NPATH; ++p) den += s_cnt[p];
        const float inv = 1.f / den;
        a.x *= inv; a.y *= inv; a.z *= inv; a.w *= inv;
        float4* hb = (float4*)(h + (size_t)b * DIN + gcol);
        hb[half * 32 + dq] = a;
    }
}

// Grid linearized 3*BATCH with g = bx % 3 so L=1/2/3 blocks interleave in
// dispatch order (x-major order previously ran all cheap L=1 first, all
// expensive L=3 last -> imbalanced tail, Occupancy 54%).
__global__ __launch_bounds__(256) void groups_kernel(
    const int* __restrict__ e1, const int* __restrict__ m1, const float* __restrict__ c1,
    const int* __restrict__ e2, const int* __restrict__ m2, const float* __restrict__ c2,
    const int* __restrict__ e3, const int* __restrict__ m3, const float* __restrict__ c3,
    const float* __restrict__ E, const float* __restrict__ W, const float* __restrict__ Bm,
    float* __restrict__ h)
{
    __shared__ int s_idx[NPATH * 7 + NPATH];
    __shared__ float4 s_red[8 * 2 * 32];
    const float4* E4 = (const float4*)E;
    const float4* W4 = (const float4*)W;
    const float4* B4 = (const float4*)Bm;
    const int bx = blockIdx.x;
    const int g = bx % 3;
    const int b = bx / 3;
    if (g == 0)      group_body<1>(b, e1, m1, c1, E4, W4, B4, h, 0,   s_idx, s_red);
    else if (g == 1) group_body<2>(b, e2, m2, c2, E4, W4, B4, h, 256, s_idx, s_red);
    else             group_body<3>(b, e3, m3, c3, E4, W4, B4, h, 512, s_idx, s_red);
}

// MLP head, register-blocked GEMM with wave-uniform (scalar) weight access.
// 64 rows/block (lane = row), 512 threads = 8 waves, wave w owns layer-1
// columns 16w..16w+15 in acc[16]. Inner loop per k: one conflict-free LDS
// b32 (hs[k][r], 2-way aliasing = free) + 16 independent FMAs with SGPR
// weight operands (W1[k][16w..] is wave-uniform -> s_load, prefetched on the
// scalar pipe). No vector-memory in the hot loop; W1 L2 traffic 403MB->25MB.
// All FMA chains ascending-k, single-chain: bitwise-identical to reference.
#define MB 64
#define KC 256
__global__ __launch_bounds__(512) void mlp_kernel(
    const float* __restrict__ h,
    const float* __restrict__ W1, const float* __restrict__ b1,
    const float* __restrict__ W2, const float* __restrict__ b2,
    const float* __restrict__ W3, const float* __restrict__ b3,
    float* __restrict__ out)
{
    __shared__ float hs[KC * MB];    // 64 KB, [k][row] transposed chunk
    __shared__ float h1s[C1 * MB];   // 32 KB, [c][row]
    __shared__ float h2s[C2 * MB];   // 8 KB,  [c2][row]

    const int tid = threadIdx.x;
    const int r = tid & 63;                                        // row lane
    const int w = __builtin_amdgcn_readfirstlane(tid >> 6);        // wave 0..7
    const int row0 = blockIdx.x * MB;

    const int cbase = w * 16;
    float acc[16];
#pragma unroll
    for (int j = 0; j < 16; ++j) acc[j] = b1[cbase + j];

    for (int ch = 0; ch < DIN / KC; ++ch) {
        const int k0 = ch * KC;
        // stage h[row0+tr][k0+kl .. +4] -> hs[kl..][tr] (transposed)
        {
            const int tr = tid >> 3;           // 0..63
            const int tc = tid & 7;
#pragma unroll
            for (int i = 0; i < KC / 32; ++i) {
                const int kl = i * 32 + tc * 4;   // lanes tc adjacent -> 128B runs
                const float4 v = *(const float4*)(h + (size_t)(row0 + tr) * DIN + k0 + kl);
                hs[(kl + 0) * MB + tr] = v.x;
                hs[(kl + 1) * MB + tr] = v.y;
                hs[(kl + 2) * MB + tr] = v.z;
                hs[(kl + 3) * MB + tr] = v.w;
            }
        }
        __syncthreads();

        const float* w1p = W1 + (size_t)k0 * C1 + cbase;   // wave-uniform
#pragma unroll 4
        for (int k = 0; k < KC; ++k) {
            const float hk = hs[k * MB + r];
            const float* w1k = w1p + (size_t)k * C1;       // wave-uniform
#pragma unroll
            for (int j = 0; j < 16; ++j)
                acc[j] = fmaf(hk, w1k[j], acc[j]);
        }
        __syncthreads();   // before next chunk overwrites hs
    }

    // relu -> h1s transposed [c][row]; write is conflict-free (2-way)
#pragma unroll
    for (int j = 0; j < 16; ++j)
        h1s[(cbase + j) * MB + r] = fmaxf(acc[j], 0.f);
    __syncthreads();

    // layer 2: wave w owns c2 = 4w..4w+3
    {
        const int c2b = w * 4;
        float a2[4];
#pragma unroll
        for (int j = 0; j < 4; ++j) a2[j] = b2[c2b + j];
        for (int k = 0; k < C1; ++k) {
            const float hk = h1s[k * MB + r];
            const float* w2k = W2 + (size_t)k * C2 + c2b;  // wave-uniform
#pragma unroll
            for (int j = 0; j < 4; ++j)
                a2[j] = fmaf(hk, w2k[j], a2[j]);
        }
#pragma unroll
        for (int j = 0; j < 4; ++j)
            h2s[(c2b + j) * MB + r] = fmaxf(a2[j], 0.f);
    }
    __syncthreads();

    // layer 3: one row per lane of wave 0
    if (tid < MB) {
        float a = b3[0];
#pragma unroll
        for (int k = 0; k < C2; ++k)
            a = fmaf(h2s[k * MB + tid], W3[k], a);
        out[row0 + tid] = a;
    }
}

extern "C" void kernel_launch(void* const* d_in, const int* in_sizes, int n_in,
                              void* d_out, int out_size, void* d_ws, size_t ws_size,
                              hipStream_t stream) {
    const int*   ent1 = (const int*)d_in[0];
    const int*   mid1 = (const int*)d_in[1];
    const float* cnt1 = (const float*)d_in[2];
    const int*   ent2 = (const int*)d_in[3];
    const int*   mid2 = (const int*)d_in[4];
    const float* cnt2 = (const float*)d_in[5];
    const int*   ent3 = (const int*)d_in[6];
    const int*   mid3 = (const int*)d_in[7];
    const float* cnt3 = (const float*)d_in[8];
    const float* E    = (const float*)d_in[9];
    const float* W    = (const float*)d_in[10];
    const float* Bm   = (const float*)d_in[11];
    const float* W1   = (const float*)d_in[12];
    const float* b1   = (const float*)d_in[13];
    const float* W2   = (const float*)d_in[14];
    const float* b2   = (const float*)d_in[15];
    const float* W3   = (const float*)d_in[16];
    const float* b3   = (const float*)d_in[17];

    float* h = (float*)d_ws;   // [BATCH, 768]
    float* out = (float*)d_out;

    groups_kernel<<<3 * BATCH, 256, 0, stream>>>(ent1, mid1, cnt1, ent2, mid2, cnt2,
                                                 ent3, mid3, cnt3, E, W, Bm, h);
    mlp_kernel<<<BATCH / MB, 512, 0, stream>>>(h, W1, b1, W2, b2, W3, b3, out);
}

// Round 5
// 223.307 us; speedup vs baseline: 1.1783x; 1.1783x over previous
//
#include <hip/hip_runtime.h>

#define EMBED 128
#define NPATH 32
#define BATCH 4096
#define DIN 768
#define C1 128
#define C2 32

__device__ __forceinline__ float4 chain_step(float4 x, float4 y, float4 wm, float4 bm) {
    float4 r;
    r.x = fmaxf(fmaf(x.x * wm.x, y.x, bm.x), 0.f);
    r.y = fmaxf(fmaf(x.y * wm.y, y.y, bm.y), 0.f);
    r.z = fmaxf(fmaf(x.z * wm.z, y.z, bm.z), 0.f);
    r.w = fmaxf(fmaf(x.w * wm.w, y.w, bm.w), 0.f);
    return r;
}

// One group-unit for batch row b. 256 threads: dl = tid&31 owns dims 4*dl..4*dl+3
// (float4), pq = tid>>5 (0..7) owns paths p = pq, pq+8, pq+16, pq+24.
// W/B selection by metapath id is now an LDS gather (mi uniform over each
// 32-lane dl-group -> two half-wave-contiguous b128 reads, conflict-free),
// fetched once per (path, step) and REUSED by fwd+bwd chains — replaces
// 4 sel3q = 32 v_cndmask per step (~half the old VALU work). Same values,
// same FMA order as the verified round-0 kernel -> bitwise identical.
template<int L>
__device__ __forceinline__ void group_body(
    int b, const int* __restrict__ ent, const int* __restrict__ mid,
    const float* __restrict__ counts, const float4* __restrict__ E4,
    const float4* __restrict__ W4, const float4* __restrict__ B4,
    float* __restrict__ h, int gcol, int* s_idx, float4* s_red, float4* s_wb)
{
    const int tid = threadIdx.x;
    const int dl = tid & 31;
    const int pq = tid >> 5;

    int* s_ent = s_idx;
    int* s_mid = s_idx + NPATH * (L + 1);
    float* s_cnt = (float*)(s_idx + NPATH * (2 * L + 1));
    float4* s_w4 = s_wb;          // [3][32] float4
    float4* s_b4 = s_wb + 96;     // [3][32] float4

    const int* entb = ent + (size_t)b * (NPATH * (L + 1));
    const int* midb = mid + (size_t)b * (NPATH * L);
    for (int i = tid; i < NPATH * (L + 1); i += 256) s_ent[i] = entb[i];
    for (int i = tid; i < NPATH * L; i += 256) s_mid[i] = midb[i];
    if (tid < NPATH) s_cnt[tid] = counts[(size_t)b * NPATH + tid];
    if (tid < 96) { s_w4[tid] = W4[tid]; s_b4[tid] = B4[tid]; }
    __syncthreads();

    float4 n1 = make_float4(0.f, 0.f, 0.f, 0.f);
    float4 n2 = make_float4(0.f, 0.f, 0.f, 0.f);

#pragma unroll 2
    for (int j = 0; j < NPATH / 8; ++j) {
        const int p = pq + 8 * j;
        int ei[L + 1], mi[L];
#pragma unroll
        for (int i = 0; i <= L; ++i) ei[i] = s_ent[p * (L + 1) + i];
#pragma unroll
        for (int i = 0; i < L; ++i) mi[i] = s_mid[p * L + i];

        float4 e[L + 1];
#pragma unroll
        for (int i = 0; i <= L; ++i) e[i] = E4[(size_t)ei[i] * 32 + dl];

        float4 wv[L], bv[L];
#pragma unroll
        for (int i = 0; i < L; ++i) {
            wv[i] = s_w4[mi[i] * 32 + dl];
            bv[i] = s_b4[mi[i] * 32 + dl];
        }
        const float c = s_cnt[p];

        float4 x = e[0];
#pragma unroll
        for (int i = 0; i < L; ++i)
            x = chain_step(x, e[i + 1], wv[i], bv[i]);

        const float4 yl = e[L];
        float4 x2 = yl;
#pragma unroll
        for (int i = L - 1; i >= 0; --i)
            x2 = chain_step(x2, yl, wv[i], bv[i]);

        n1.x = fmaf(c, x.x, n1.x); n1.y = fmaf(c, x.y, n1.y);
        n1.z = fmaf(c, x.z, n1.z); n1.w = fmaf(c, x.w, n1.w);
        n2.x = fmaf(c, x2.x, n2.x); n2.y = fmaf(c, x2.y, n2.y);
        n2.z = fmaf(c, x2.z, n2.z); n2.w = fmaf(c, x2.w, n2.w);
    }

    s_red[(pq * 2 + 0) * 32 + dl] = n1;
    s_red[(pq * 2 + 1) * 32 + dl] = n2;
    __syncthreads();
    if (tid < 64) {
        const int half = tid >> 5, dq = tid & 31;
        float4 a = s_red[(0 * 2 + half) * 32 + dq];
#pragma unroll
        for (int q = 1; q < 8; ++q) {
            float4 t = s_red[(q * 2 + half) * 32 + dq];
            a.x += t.x; a.y += t.y; a.z += t.z; a.w += t.w;
        }
        float den = 0.f;
#pragma unroll
        for (int p = 0; p < NPATH; ++p) den += s_cnt[p];
        const float inv = 1.f / den;
        a.x *= inv; a.y *= inv; a.z *= inv; a.w *= inv;
        float4* hb = (float4*)(h + (size_t)b * DIN + gcol);
        hb[half * 32 + dq] = a;
    }
}

// Grid linearized 3*BATCH with g = bx % 3 so L=1/2/3 blocks interleave in
// dispatch order (even load through the tail).
__global__ __launch_bounds__(256) void groups_kernel(
    const int* __restrict__ e1, const int* __restrict__ m1, const float* __restrict__ c1,
    const int* __restrict__ e2, const int* __restrict__ m2, const float* __restrict__ c2,
    const int* __restrict__ e3, const int* __restrict__ m3, const float* __restrict__ c3,
    const float* __restrict__ E, const float* __restrict__ W, const float* __restrict__ Bm,
    float* __restrict__ h)
{
    __shared__ int s_idx[NPATH * 7 + NPATH];
    __shared__ float4 s_red[8 * 2 * 32];
    __shared__ float4 s_wb[192];            // W[3][32] + B[3][32] float4
    const float4* E4 = (const float4*)E;
    const float4* W4 = (const float4*)W;
    const float4* B4 = (const float4*)Bm;
    const int bx = blockIdx.x;
    const int g = bx % 3;
    const int b = bx / 3;
    if (g == 0)      group_body<1>(b, e1, m1, c1, E4, W4, B4, h, 0,   s_idx, s_red, s_wb);
    else if (g == 1) group_body<2>(b, e2, m2, c2, E4, W4, B4, h, 256, s_idx, s_red, s_wb);
    else             group_body<3>(b, e3, m3, c3, E4, W4, B4, h, 512, s_idx, s_red, s_wb);
}

// MLP head, round-0 structure (512 blocks, 256 thr, 8 rows, acc[4]/thread,
// identical FMA order) but with W1 staged through LDS in K-chunks of 96:
// the hot loop has ZERO global loads — 4 stride-1 ds_read_b32 (2-way = free)
// + 4 broadcast b128 + 16 FMA, no vmcnt stalls. W1 L2 traffic 403->201 MB,
// fetched bulk-coalesced (12 independent float4/thread/chunk, one wait).
// LDS 77 KB -> 2 blocks/CU (same occupancy as round 0, minus the stall).
#define MROWS 8
#define KC 96
__global__ __launch_bounds__(256) void mlp_kernel(
    const float* __restrict__ h,
    const float* __restrict__ W1, const float* __restrict__ b1,
    const float* __restrict__ W2, const float* __restrict__ b2,
    const float* __restrict__ W3, const float* __restrict__ b3,
    float* __restrict__ out)
{
    __shared__ float hs[MROWS * DIN];     // 24 KB
    __shared__ float w1s[KC * C1];        // 48 KB
    __shared__ float h1[MROWS][C1];       // 4 KB
    __shared__ float h2[MROWS][C2];       // 1 KB

    const int tid = threadIdx.x;
    const int c = tid & 127;          // layer-1 column
    const int rh = tid >> 7;          // 0..1, owns rows rh*4 .. rh*4+3
    const int row0 = blockIdx.x * MROWS;

    {
        const float4* src = (const float4*)(h + (size_t)row0 * DIN);
        float4* dst = (float4*)hs;
#pragma unroll
        for (int i = 0; i < (MROWS * DIN / 4) / 256; ++i)      // 6
            dst[tid + i * 256] = src[tid + i * 256];
    }

    float acc[4];
    const float bias1 = b1[c];
#pragma unroll
    for (int r = 0; r < 4; ++r) acc[r] = bias1;

    const float* hrow = hs + rh * 4 * DIN;
    for (int ch = 0; ch < DIN / KC; ++ch) {                    // 8 chunks
        {   // stage W1[ch*KC .. +KC)[*] -> w1s (same [k][c] layout, coalesced)
            const float4* wsrc = (const float4*)(W1 + (size_t)ch * KC * C1);
            float4* wdst = (float4*)w1s;
#pragma unroll
            for (int i = 0; i < (KC * C1 / 4) / 256; ++i)      // 12
                wdst[tid + i * 256] = wsrc[tid + i * 256];
        }
        __syncthreads();   // w1s ready (covers hs on ch==0)

        const int kb = ch * KC;
#pragma unroll 4
        for (int k0 = 0; k0 < KC; k0 += 4) {
            const float w0 = w1s[(k0 + 0) * C1 + c];
            const float w1v = w1s[(k0 + 1) * C1 + c];
            const float w2v = w1s[(k0 + 2) * C1 + c];
            const float w3v = w1s[(k0 + 3) * C1 + c];
#pragma unroll
            for (int r = 0; r < 4; ++r) {
                const float4 hq = *(const float4*)(hrow + r * DIN + kb + k0);
                acc[r] = fmaf(hq.x, w0, acc[r]);
                acc[r] = fmaf(hq.y, w1v, acc[r]);
                acc[r] = fmaf(hq.z, w2v, acc[r]);
                acc[r] = fmaf(hq.w, w3v, acc[r]);
            }
        }
        __syncthreads();   // before next chunk overwrites w1s
    }

#pragma unroll
    for (int r = 0; r < 4; ++r) h1[rh * 4 + r][c] = fmaxf(acc[r], 0.f);
    __syncthreads();

    // layer 2: 8 rows x 32 cols = 256 outputs, one per thread
    {
        const int r = tid >> 5;           // 0..7
        const int c2 = tid & 31;
        float a = b2[c2];
#pragma unroll
        for (int k = 0; k < C1; ++k)
            a = fmaf(h1[r][k], W2[k * C2 + c2], a);
        h2[r][c2] = fmaxf(a, 0.f);
    }
    __syncthreads();

    // layer 3
    if (tid < MROWS) {
        float a = b3[0];
#pragma unroll
        for (int k = 0; k < C2; ++k)
            a = fmaf(h2[tid][k], W3[k], a);
        out[row0 + tid] = a;
    }
}

extern "C" void kernel_launch(void* const* d_in, const int* in_sizes, int n_in,
                              void* d_out, int out_size, void* d_ws, size_t ws_size,
                              hipStream_t stream) {
    const int*   ent1 = (const int*)d_in[0];
    const int*   mid1 = (const int*)d_in[1];
    const float* cnt1 = (const float*)d_in[2];
    const int*   ent2 = (const int*)d_in[3];
    const int*   mid2 = (const int*)d_in[4];
    const float* cnt2 = (const float*)d_in[5];
    const int*   ent3 = (const int*)d_in[6];
    const int*   mid3 = (const int*)d_in[7];
    const float* cnt3 = (const float*)d_in[8];
    const float* E    = (const float*)d_in[9];
    const float* W    = (const float*)d_in[10];
    const float* Bm   = (const float*)d_in[11];
    const float* W1   = (const float*)d_in[12];
    const float* b1   = (const float*)d_in[13];
    const float* W2   = (const float*)d_in[14];
    const float* b2   = (const float*)d_in[15];
    const float* W3   = (const float*)d_in[16];
    const float* b3   = (const float*)d_in[17];

    float* h = (float*)d_ws;   // [BATCH, 768]
    float* out = (float*)d_out;

    groups_kernel<<<3 * BATCH, 256, 0, stream>>>(ent1, mid1, cnt1, ent2, mid2, cnt2,
                                                 ent3, mid3, cnt3, E, W, Bm, h);
    mlp_kernel<<<BATCH / MROWS, 256, 0, stream>>>(h, W1, b1, W2, b2, W3, b3, out);
}

// Round 6
// 218.324 us; speedup vs baseline: 1.2052x; 1.0228x over previous
//
#include <hip/hip_runtime.h>

#define EMBED 128
#define NPATH 32
#define BATCH 4096
#define DIN 768
#define C1 128
#define C2 32

__device__ __forceinline__ float4 chain_step(float4 x, float4 y, float4 wm, float4 bm) {
    float4 r;
    r.x = fmaxf(fmaf(x.x * wm.x, y.x, bm.x), 0.f);
    r.y = fmaxf(fmaf(x.y * wm.y, y.y, bm.y), 0.f);
    r.z = fmaxf(fmaf(x.z * wm.z, y.z, bm.z), 0.f);
    r.w = fmaxf(fmaf(x.w * wm.w, y.w, bm.w), 0.f);
    return r;
}

// One group-unit for batch row b. 256 threads: dl = tid&31 owns dims 4*dl..4*dl+3
// (float4), pq = tid>>5 (0..7) owns paths p = pq, pq+8, pq+16, pq+24.
// FINAL (round 5 verified): memory-pattern-bound at 3.5 TB/s / ~83us — four
// structural variants all plateau here; random 512B gathers over the 51MB
// E-table are the floor. W/B selection via LDS gather (VALU-lean, Occ 62%).
template<int L>
__device__ __forceinline__ void group_body(
    int b, const int* __restrict__ ent, const int* __restrict__ mid,
    const float* __restrict__ counts, const float4* __restrict__ E4,
    const float4* __restrict__ W4, const float4* __restrict__ B4,
    float* __restrict__ h, int gcol, int* s_idx, float4* s_red, float4* s_wb)
{
    const int tid = threadIdx.x;
    const int dl = tid & 31;
    const int pq = tid >> 5;

    int* s_ent = s_idx;
    int* s_mid = s_idx + NPATH * (L + 1);
    float* s_cnt = (float*)(s_idx + NPATH * (2 * L + 1));
    float4* s_w4 = s_wb;          // [3][32] float4
    float4* s_b4 = s_wb + 96;     // [3][32] float4

    const int* entb = ent + (size_t)b * (NPATH * (L + 1));
    const int* midb = mid + (size_t)b * (NPATH * L);
    for (int i = tid; i < NPATH * (L + 1); i += 256) s_ent[i] = entb[i];
    for (int i = tid; i < NPATH * L; i += 256) s_mid[i] = midb[i];
    if (tid < NPATH) s_cnt[tid] = counts[(size_t)b * NPATH + tid];
    if (tid < 96) { s_w4[tid] = W4[tid]; s_b4[tid] = B4[tid]; }
    __syncthreads();

    float4 n1 = make_float4(0.f, 0.f, 0.f, 0.f);
    float4 n2 = make_float4(0.f, 0.f, 0.f, 0.f);

#pragma unroll 2
    for (int j = 0; j < NPATH / 8; ++j) {
        const int p = pq + 8 * j;
        int ei[L + 1], mi[L];
#pragma unroll
        for (int i = 0; i <= L; ++i) ei[i] = s_ent[p * (L + 1) + i];
#pragma unroll
        for (int i = 0; i < L; ++i) mi[i] = s_mid[p * L + i];

        float4 e[L + 1];
#pragma unroll
        for (int i = 0; i <= L; ++i) e[i] = E4[(size_t)ei[i] * 32 + dl];

        float4 wv[L], bv[L];
#pragma unroll
        for (int i = 0; i < L; ++i) {
            wv[i] = s_w4[mi[i] * 32 + dl];
            bv[i] = s_b4[mi[i] * 32 + dl];
        }
        const float c = s_cnt[p];

        float4 x = e[0];
#pragma unroll
        for (int i = 0; i < L; ++i)
            x = chain_step(x, e[i + 1], wv[i], bv[i]);

        const float4 yl = e[L];
        float4 x2 = yl;
#pragma unroll
        for (int i = L - 1; i >= 0; --i)
            x2 = chain_step(x2, yl, wv[i], bv[i]);

        n1.x = fmaf(c, x.x, n1.x); n1.y = fmaf(c, x.y, n1.y);
        n1.z = fmaf(c, x.z, n1.z); n1.w = fmaf(c, x.w, n1.w);
        n2.x = fmaf(c, x2.x, n2.x); n2.y = fmaf(c, x2.y, n2.y);
        n2.z = fmaf(c, x2.z, n2.z); n2.w = fmaf(c, x2.w, n2.w);
    }

    s_red[(pq * 2 + 0) * 32 + dl] = n1;
    s_red[(pq * 2 + 1) * 32 + dl] = n2;
    __syncthreads();
    if (tid < 64) {
        const int half = tid >> 5, dq = tid & 31;
        float4 a = s_red[(0 * 2 + half) * 32 + dq];
#pragma unroll
        for (int q = 1; q < 8; ++q) {
            float4 t = s_red[(q * 2 + half) * 32 + dq];
            a.x += t.x; a.y += t.y; a.z += t.z; a.w += t.w;
        }
        float den = 0.f;
#pragma unroll
        for (int p = 0; p < NPATH; ++p) den += s_cnt[p];
        const float inv = 1.f / den;
        a.x *= inv; a.y *= inv; a.z *= inv; a.w *= inv;
        float4* hb = (float4*)(h + (size_t)b * DIN + gcol);
        hb[half * 32 + dq] = a;
    }
}

// Grid linearized 3*BATCH with g = bx % 3 so L=1/2/3 blocks interleave in
// dispatch order (even load through the tail).
__global__ __launch_bounds__(256) void groups_kernel(
    const int* __restrict__ e1, const int* __restrict__ m1, const float* __restrict__ c1,
    const int* __restrict__ e2, const int* __restrict__ m2, const float* __restrict__ c2,
    const int* __restrict__ e3, const int* __restrict__ m3, const float* __restrict__ c3,
    const float* __restrict__ E, const float* __restrict__ W, const float* __restrict__ Bm,
    float* __restrict__ h)
{
    __shared__ int s_idx[NPATH * 7 + NPATH];
    __shared__ float4 s_red[8 * 2 * 32];
    __shared__ float4 s_wb[192];            // W[3][32] + B[3][32] float4
    const float4* E4 = (const float4*)E;
    const float4* W4 = (const float4*)W;
    const float4* B4 = (const float4*)Bm;
    const int bx = blockIdx.x;
    const int g = bx % 3;
    const int b = bx / 3;
    if (g == 0)      group_body<1>(b, e1, m1, c1, E4, W4, B4, h, 0,   s_idx, s_red, s_wb);
    else if (g == 1) group_body<2>(b, e2, m2, c2, E4, W4, B4, h, 256, s_idx, s_red, s_wb);
    else             group_body<3>(b, e3, m3, c3, E4, W4, B4, h, 512, s_idx, s_red, s_wb);
}

// MLP head v5: MROWS=16, 1024 threads, 256 blocks (1 block/CU, 16 waves/CU).
// - W1 L2 redundancy: 256 x 393KB = 100 MB (~3us L2 floor; was 403 MB).
// - Inner loop batches 8 INDEPENDENT W1 dword loads (coalesced 256B/wave)
//   per 16 FMA: 16 waves x 8 x 256B = 32 KB in flight per CU -> drain time
//   (~580cy at the 56 B/cy L2-slice rate) exceeds L2 latency (~200cy), so
//   the loop is BW-saturated, not latency-exposed (the round-0..3 failure).
// - h tile (16x768 = 48KB LDS) read as wave-uniform b128 broadcasts.
// - Every output is one ascending-k FMA chain: bitwise identical to before.
#define MROWS 16
__global__ __launch_bounds__(1024) void mlp_kernel(
    const float* __restrict__ h,
    const float* __restrict__ W1, const float* __restrict__ b1,
    const float* __restrict__ W2, const float* __restrict__ b2,
    const float* __restrict__ W3, const float* __restrict__ b3,
    float* __restrict__ out)
{
    __shared__ float hs[MROWS * DIN];     // 48 KB
    __shared__ float h1[MROWS][C1];       // 8 KB
    __shared__ float h2[MROWS][C2];       // 2 KB

    const int tid = threadIdx.x;          // 0..1023
    const int c = tid & 127;              // layer-1 column
    const int rp = tid >> 7;              // 0..7, owns rows 2rp, 2rp+1
    const int row0 = blockIdx.x * MROWS;

    {   // stage h tile: 16x768 floats = 3072 float4, 3 per thread, coalesced
        const float4* src = (const float4*)(h + (size_t)row0 * DIN);
        float4* dst = (float4*)hs;
#pragma unroll
        for (int i = 0; i < 3; ++i)
            dst[tid + i * 1024] = src[tid + i * 1024];
    }
    __syncthreads();

    float acc0 = b1[c];
    float acc1 = b1[c];
    const float* h0 = hs + (2 * rp + 0) * DIN;
    const float* h1p = hs + (2 * rp + 1) * DIN;

    for (int k0 = 0; k0 < DIN; k0 += 8) {
        // 8 independent coalesced W1 loads, then 4 broadcast b128 LDS reads,
        // then 16 FMA. Chains stay k-ascending.
        float w0 = W1[(k0 + 0) * C1 + c];
        float w1 = W1[(k0 + 1) * C1 + c];
        float w2 = W1[(k0 + 2) * C1 + c];
        float w3 = W1[(k0 + 3) * C1 + c];
        float w4 = W1[(k0 + 4) * C1 + c];
        float w5 = W1[(k0 + 5) * C1 + c];
        float w6 = W1[(k0 + 6) * C1 + c];
        float w7 = W1[(k0 + 7) * C1 + c];

        const float4 a0 = *(const float4*)(h0 + k0);
        const float4 a1 = *(const float4*)(h0 + k0 + 4);
        const float4 b0 = *(const float4*)(h1p + k0);
        const float4 b1q = *(const float4*)(h1p + k0 + 4);

        acc0 = fmaf(a0.x, w0, acc0);
        acc0 = fmaf(a0.y, w1, acc0);
        acc0 = fmaf(a0.z, w2, acc0);
        acc0 = fmaf(a0.w, w3, acc0);
        acc0 = fmaf(a1.x, w4, acc0);
        acc0 = fmaf(a1.y, w5, acc0);
        acc0 = fmaf(a1.z, w6, acc0);
        acc0 = fmaf(a1.w, w7, acc0);

        acc1 = fmaf(b0.x, w0, acc1);
        acc1 = fmaf(b0.y, w1, acc1);
        acc1 = fmaf(b0.z, w2, acc1);
        acc1 = fmaf(b0.w, w3, acc1);
        acc1 = fmaf(b1q.x, w4, acc1);
        acc1 = fmaf(b1q.y, w5, acc1);
        acc1 = fmaf(b1q.z, w6, acc1);
        acc1 = fmaf(b1q.w, w7, acc1);
    }

    h1[2 * rp + 0][c] = fmaxf(acc0, 0.f);
    h1[2 * rp + 1][c] = fmaxf(acc1, 0.f);
    __syncthreads();

    // layer 2: 16 rows x 32 cols = 512 outputs on threads 0..511
    if (tid < MROWS * C2) {
        const int r = tid >> 5;           // 0..15
        const int c2 = tid & 31;
        float a = b2[c2];
#pragma unroll
        for (int k = 0; k < C1; ++k)
            a = fmaf(h1[r][k], W2[k * C2 + c2], a);
        h2[r][c2] = fmaxf(a, 0.f);
    }
    __syncthreads();

    // layer 3
    if (tid < MROWS) {
        float a = b3[0];
#pragma unroll
        for (int k = 0; k < C2; ++k)
            a = fmaf(h2[tid][k], W3[k], a);
        out[row0 + tid] = a;
    }
}

extern "C" void kernel_launch(void* const* d_in, const int* in_sizes, int n_in,
                              void* d_out, int out_size, void* d_ws, size_t ws_size,
                              hipStream_t stream) {
    const int*   ent1 = (const int*)d_in[0];
    const int*   mid1 = (const int*)d_in[1];
    const float* cnt1 = (const float*)d_in[2];
    const int*   ent2 = (const int*)d_in[3];
    const int*   mid2 = (const int*)d_in[4];
    const float* cnt2 = (const float*)d_in[5];
    const int*   ent3 = (const int*)d_in[6];
    const int*   mid3 = (const int*)d_in[7];
    const float* cnt3 = (const float*)d_in[8];
    const float* E    = (const float*)d_in[9];
    const float* W    = (const float*)d_in[10];
    const float* Bm   = (const float*)d_in[11];
    const float* W1   = (const float*)d_in[12];
    const float* b1   = (const float*)d_in[13];
    const float* W2   = (const float*)d_in[14];
    const float* b2   = (const float*)d_in[15];
    const float* W3   = (const float*)d_in[16];
    const float* b3   = (const float*)d_in[17];

    float* h = (float*)d_ws;   // [BATCH, 768]
    float* out = (float*)d_out;

    groups_kernel<<<3 * BATCH, 256, 0, stream>>>(ent1, mid1, cnt1, ent2, mid2, cnt2,
                                                 ent3, mid3, cnt3, E, W, Bm, h);
    mlp_kernel<<<BATCH / MROWS, 1024, 0, stream>>>(h, W1, b1, W2, b2, W3, b3, out);
}